// Round 4
// baseline (6034.286 us; speedup 1.0000x reference)
//
#include <hip/hip_runtime.h>

// Neural ODE RK4 scan: 1024 independent batch rows, one block (4 waves) per row.
// Wave w owns hidden slice j in [64w, 64w+64). Weights live in 32 individually
// NAMED float4 VGPR variables (no allocas -> nothing for SROA to miss).
// LDS: wave-private x/activation broadcast buffers + stride-5 conflict-free
// cross-wave partial exchange; exactly 1 raw s_barrier per eval.

#define NB 1024
#define ND 64
#define NH 256

#define R16(M) M(0) M(1) M(2) M(3) M(4) M(5) M(6) M(7) \
               M(8) M(9) M(10) M(11) M(12) M(13) M(14) M(15)

__device__ __forceinline__ float fast_tanh(float x) {
    // tanh(x) = 1 - 2/(1+e^{2x})
    float e = __expf(2.0f * x);
    float r = __builtin_amdgcn_rcpf(e + 1.0f);
    return 1.0f - 2.0f * r;
}

// lgkmcnt(0) then barrier: part-write visible; no vmcnt drain (output stores
// from previous steps keep flowing).
#define BLOCK_SYNC() do {                                        \
    asm volatile("s_waitcnt lgkmcnt(0)" ::: "memory");           \
    __builtin_amdgcn_s_barrier();                                \
    asm volatile("" ::: "memory");                               \
} while (0)

// GEMM1 step q: h += W1c_q * xbuf[4q..4q+3]  (uniform-addr LDS broadcast)
#define G1(q) { float4 xv = xv4[q];                              \
    h0 = fmaf(W1c##q.x, xv.x, h0);                               \
    h1 = fmaf(W1c##q.y, xv.y, h1);                               \
    h0 = fmaf(W1c##q.z, xv.z, h0);                               \
    h1 = fmaf(W1c##q.w, xv.w, h1); }

// GEMM2 step q: p += a[4q..4q+3] * W2r_q
#define G2(q) { float4 av = av4[q];                              \
    p0 = fmaf(av.x, W2r##q.x, p0);                               \
    p1 = fmaf(av.y, W2r##q.y, p1);                               \
    p0 = fmaf(av.z, W2r##q.z, p0);                               \
    p1 = fmaf(av.w, W2r##q.w, p1); }

// One func eval: KOUT = (tanh(XIN@W1+b1)@W2+b2)[l]; XIN/KOUT elem-per-lane,
// replicated across the 4 waves (each wave holds the full 64-vector).
#define EVAL(XIN, KOUT) do {                                     \
    xbuf[w][l] = (XIN);                                          \
    float h0 = b1l, h1 = 0.0f;                                   \
    R16(G1)                                                      \
    float a = fast_tanh(h0 + h1);                                \
    abuf[w][l] = a;                                              \
    float p0 = 0.0f, p1 = 0.0f;                                  \
    R16(G2)                                                      \
    part[pb][l][w] = p0 + p1;                                    \
    BLOCK_SYNC();                                                \
    KOUT = ((part[pb][l][0] + part[pb][l][1]) +                  \
            (part[pb][l][2] + part[pb][l][3])) + b2l;            \
    pb ^= 1;  /* WAR separated by next eval's barrier */         \
} while (0)

// Named-register weight declarations / loads (coalesced: lane-consecutive).
#define DECLW(q) float4 W1c##q, W2r##q;
#define LOADW(q)                                                 \
    W1c##q.x = W1[(4*q + 0) * NH + j];                           \
    W1c##q.y = W1[(4*q + 1) * NH + j];                           \
    W1c##q.z = W1[(4*q + 2) * NH + j];                           \
    W1c##q.w = W1[(4*q + 3) * NH + j];                           \
    W2r##q.x = W2[((w << 6) + 4*q + 0) * ND + l];                \
    W2r##q.y = W2[((w << 6) + 4*q + 1) * ND + l];                \
    W2r##q.z = W2[((w << 6) + 4*q + 2) * ND + l];                \
    W2r##q.w = W2[((w << 6) + 4*q + 3) * ND + l];

__global__ __launch_bounds__(256, 2)
void node_rk4_kernel(const float* __restrict__ y0,
                     const float* __restrict__ t,
                     const float* __restrict__ W1,
                     const float* __restrict__ b1,
                     const float* __restrict__ W2,
                     const float* __restrict__ b2,
                     float* __restrict__ out,
                     int nsteps)
{
    const int row = blockIdx.x;
    const int tid = threadIdx.x;
    const int w   = tid >> 6;        // wave -> hidden slice
    const int l   = tid & 63;        // lane -> dim index / hidden offset
    const int j   = (w << 6) + l;    // owned hidden unit

    __shared__ __align__(16) float xbuf[4][ND];   // wave-private input bcast
    __shared__ __align__(16) float abuf[4][ND];   // wave-private activation bcast
    __shared__ float part[2][ND][5];              // stride-5: conflict-free

    R16(DECLW)
    R16(LOADW)
    const float b1l = b1[j];
    const float b2l = b2[l];

    const float4* xv4 = reinterpret_cast<const float4*>(&xbuf[w][0]);
    const float4* av4 = reinterpret_cast<const float4*>(&abuf[w][0]);

    float y = y0[row * ND + l];
    if (w == 0) out[row * ND + l] = y;   // step-0 output = y0

    int pb = 0;

    for (int s = 0; s < nsteps; ++s) {
        float h  = t[s + 1] - t[s];      // func is autonomous; only h matters
        float hh = 0.5f * h;
        float k1, k2, k3, k4;
        EVAL(y, k1);
        EVAL(fmaf(hh, k1, y), k2);
        EVAL(fmaf(hh, k2, y), k3);
        EVAL(fmaf(h,  k3, y), k4);
        y = fmaf(h * (1.0f / 6.0f), (k1 + k4) + 2.0f * (k2 + k3), y);
        if (w == 0)                      // waves hold identical y; store once
            out[(size_t)(s + 1) * (NB * ND) + row * ND + l] = y;
    }
}

extern "C" void kernel_launch(void* const* d_in, const int* in_sizes, int n_in,
                              void* d_out, int out_size, void* d_ws, size_t ws_size,
                              hipStream_t stream) {
    const float* y0 = (const float*)d_in[0];
    const float* t  = (const float*)d_in[1];
    const float* W1 = (const float*)d_in[2];
    const float* b1 = (const float*)d_in[3];
    const float* W2 = (const float*)d_in[4];
    const float* b2 = (const float*)d_in[5];
    float* out = (float*)d_out;
    int nsteps = in_sizes[1] - 1;
    hipLaunchKernelGGL(node_rk4_kernel, dim3(NB), dim3(256), 0, stream,
                       y0, t, W1, b1, W2, b2, out, nsteps);
}